// Round 1
// 329.681 us; speedup vs baseline: 1.0072x; 1.0072x over previous
//
#include <hip/hip_runtime.h>

#define BLOCK 256
#define ROWS  256                 // rows per block (1 per thread)
#define PCF4  (ROWS * 3 / 4)      // 192 float4 per block for prnt/child
#define EPSF4 (ROWS * 9 / 4)      // 576 float4 per block for eps

typedef const __attribute__((address_space(1))) void* gas1_t;
typedef __attribute__((address_space(3)))       void* las3_t;

// Async direct-to-LDS 16B load: lane L of the wave loads g[L] (1KB/wave per
// issue) into LDS at (wave-uniform) l + L*16. Drained by __syncthreads()
// (compiler emits s_waitcnt vmcnt(0) before s_barrier).
__device__ __forceinline__ void ld_lds16(const float4* g, float4* l) {
    __builtin_amdgcn_global_load_lds((gas1_t)(const void*)g, (las3_t)(void*)l, 16, 0, 0);
}

// 16.9 KB LDS, <=64 VGPR -> 8 blocks/CU (32 waves = full occupancy).
__global__ __launch_bounds__(BLOCK, 8) void alpha_kernel(
    const float4* __restrict__ prnt4,
    const float4* __restrict__ child4,
    const float*  __restrict__ rel_mu,
    const float*  __restrict__ rel_sigma,
    const float4* __restrict__ eps4,
    const float*  __restrict__ beta,
    const int*    __restrict__ rels,
    float*  __restrict__ out0,   // copy_mask        (N floats)
    float4* __restrict__ out1,   // child_probs2copy (3N floats)
    float*  __restrict__ out2,   // alpha_mask       (N floats)
    float4* __restrict__ out3,   // alpha            (3N floats)
    int n_rows, int nmu)
{
    __shared__ float4 s_p[PCF4];
    __shared__ float4 s_c[PCF4];
    __shared__ float4 s_e[EPSF4];
    __shared__ float  smu[192];
    __shared__ float  ssg[192];

    const int  tid       = threadIdx.x;
    const int  lane      = tid & 63;
    const int  wv        = tid >> 6;          // 4 waves per block
    const int  b         = blockIdx.x;
    const long rows_base = (long)b * ROWS;
    const int  rows_here = min(ROWS, (int)(n_rows - rows_base));
    const bool full      = (rows_here == ROWS);

    const float4* gp = prnt4  + (size_t)b * PCF4;
    const float4* gc = child4 + (size_t)b * PCF4;
    const float4* ge = eps4   + (size_t)b * EPSF4;

    // --- scalar loads issued first so their waitcnt doesn't drain the async queue
    float rmu = 0.0f, rsg = 0.0f;
    const bool has_mu = (tid < nmu);
    if (has_mu) { rmu = rel_mu[tid]; rsg = rel_sigma[tid]; }

    const bool active = (tid < rows_here);
    float bt = 0.0f;
    int   rq = 0;
    if (active) {
        bt = beta[rows_base + tid];
        rq = rels[rows_base + tid];
    }

    // --- async global->LDS staging, 64-float4 (1KB) chunks per wave issue
    if (full) {
        for (int c = wv; c < PCF4 / 64; c += 4) {          // 3 chunks total
            ld_lds16(gp + (c << 6) + lane, s_p + (c << 6));
            ld_lds16(gc + (c << 6) + lane, s_c + (c << 6));
        }
        for (int c = wv; c < EPSF4 / 64; c += 4) {         // 9 chunks total
            ld_lds16(ge + (c << 6) + lane, s_e + (c << 6));
        }
    } else {
        const int pcf4_here  = rows_here * 3 / 4;
        const int epsf4_here = rows_here * 9 / 4;
        const int pc_chunks  = pcf4_here >> 6;
        const int eps_chunks = epsf4_here >> 6;
        for (int c = wv; c < pc_chunks; c += 4) {
            ld_lds16(gp + (c << 6) + lane, s_p + (c << 6));
            ld_lds16(gc + (c << 6) + lane, s_c + (c << 6));
        }
        for (int c = wv; c < eps_chunks; c += 4) {
            ld_lds16(ge + (c << 6) + lane, s_e + (c << 6));
        }
        // remainders (none for N=4M, kept for generality)
        for (int i = (pc_chunks << 6) + tid; i < pcf4_here; i += BLOCK) {
            s_p[i] = gp[i];
            s_c[i] = gc[i];
        }
        for (int i = (eps_chunks << 6) + tid; i < epsf4_here; i += BLOCK) {
            s_e[i] = ge[i];
        }
    }

    if (has_mu) { smu[tid] = rmu; ssg[tid] = rsg; }
    __syncthreads();

    float o1[3], o3[3];
    float m0 = 0.0f, m2 = 0.0f;

    if (active) {
        const float* pf = (const float*)s_p;
        const float* cf = (const float*)s_c;
        const float* ef = (const float*)s_e;

        // strides 3 and 9 are coprime with 32 banks -> conflict-free
        float p[3], c[3], e[9];
        #pragma unroll
        for (int k = 0; k < 3; ++k) p[k] = pf[3 * tid + k];
        #pragma unroll
        for (int k = 0; k < 3; ++k) c[k] = cf[3 * tid + k];
        #pragma unroll
        for (int k = 0; k < 9; ++k) e[k] = ef[9 * tid + k];

        const float* mu = &smu[9 * rq];
        const float* sg = &ssg[9 * rq];

        // logits = (mu + sigma*eps) @ child
        float l[3];
        #pragma unroll
        for (int i = 0; i < 3; ++i) {
            float acc = 0.0f;
            #pragma unroll
            for (int j = 0; j < 3; ++j) {
                float m = fmaf(sg[3 * i + j], e[3 * i + j], mu[3 * i + j]);
                acc = fmaf(m, c[j], acc);
            }
            l[i] = acc;
        }
        // softmax (3-wide)
        float mx = fmaxf(l[0], fmaxf(l[1], l[2]));
        float e0 = __expf(l[0] - mx), e1 = __expf(l[1] - mx), e2 = __expf(l[2] - mx);
        float einv = 1.0f / (e0 + e1 + e2);
        float cp0 = e0 * einv, cp1 = e1 * einv, cp2 = e2 * einv;

        float csum = c[0] + c[1] + c[2];
        float psum = p[0] + p[1] + p[2];
        bool cmask = (csum != 0.0f);
        bool copy  = cmask && (psum == 0.0f);
        bool amask = cmask && (psum != 0.0f);

        // _scale(prnt, cp)
        float z0 = fmaxf(0.01f, p[0] + cp0);
        float z1 = fmaxf(0.01f, p[1] + cp1);
        float z2 = fmaxf(0.01f, p[2] + cp2);
        float zinv = 1.0f / (z0 + z1 + z2);
        z0 *= zinv; z1 *= zinv; z2 *= zinv;
        float ent = -(z0 * __logf(z0) + z1 * __logf(z1) + z2 * __logf(z2));
        float cosv = p[0] * cp0 + p[1] * cp1 + p[2] * cp2;
        float np2 = p[0] * p[0] + p[1] * p[1] + p[2] * p[2];
        float nc2 = cp0 * cp0 + cp1 * cp1 + cp2 * cp2;
        float npn = (np2 == 0.0f) ? 0.0f : sqrtf(np2);
        float ncn = (nc2 == 0.0f) ? 0.0f : sqrtf(nc2);
        float nrm = npn * ncn;
        nrm = (nrm == 0.0f) ? 1.0f : nrm;
        cosv = fmaxf(0.01f, cosv / nrm);
        float s = 42.0f * cosv / ent;

        float bb = bt, ob = 1.0f - bb;
        float a0 = fmaf(ob, p[0], bb * cp0) * s;
        float a1 = fmaf(ob, p[1], bb * cp1) * s;
        float a2 = fmaf(ob, p[2], bb * cp2) * s;

        m0 = copy  ? 1.0f : 0.0f;
        m2 = amask ? 1.0f : 0.0f;
        o1[0] = copy ? cp0 : 0.0f;
        o1[1] = copy ? cp1 : 0.0f;
        o1[2] = copy ? cp2 : 0.0f;
        o3[0] = amask ? a0 : 0.0f;
        o3[1] = amask ? a1 : 0.0f;
        o3[2] = amask ? a2 : 0.0f;
    }

    // All LDS input reads complete -> safe to reuse s_p/s_c for outputs.
    __syncthreads();

    if (active) {
        float* of1 = (float*)s_p;
        float* of3 = (float*)s_c;
        #pragma unroll
        for (int k = 0; k < 3; ++k) of1[3 * tid + k] = o1[k];
        #pragma unroll
        for (int k = 0; k < 3; ++k) of3[3 * tid + k] = o3[k];
        out0[rows_base + tid] = m0;
        out2[rows_base + tid] = m2;
    }
    __syncthreads();

    float4* g1 = out1 + (size_t)b * PCF4;
    float4* g3 = out3 + (size_t)b * PCF4;
    const int pcf4_here = rows_here * 3 / 4;
    for (int i = tid; i < pcf4_here; i += BLOCK) {
        g1[i] = s_p[i];
        g3[i] = s_c[i];
    }
}

extern "C" void kernel_launch(void* const* d_in, const int* in_sizes, int n_in,
                              void* d_out, int out_size, void* d_ws, size_t ws_size,
                              hipStream_t stream)
{
    const float* prnt      = (const float*)d_in[0];
    const float* child     = (const float*)d_in[1];
    const float* rel_mu    = (const float*)d_in[2];
    const float* rel_sigma = (const float*)d_in[3];
    const float* eps       = (const float*)d_in[4];
    const float* beta      = (const float*)d_in[5];
    const int*   rels      = (const int*)d_in[6];

    const int N   = in_sizes[5];   // 4,000,000
    const int nmu = in_sizes[2];   // 180

    float* out  = (float*)d_out;
    float* out0 = out;                      // copy_mask        [N]
    float* out1 = out + (size_t)N;          // child_probs2copy [N,3]
    float* out2 = out + (size_t)4 * N;      // alpha_mask       [N]
    float* out3 = out + (size_t)5 * N;      // alpha            [N,3]

    int blocks = (N + ROWS - 1) / ROWS;
    alpha_kernel<<<blocks, BLOCK, 0, stream>>>(
        (const float4*)prnt, (const float4*)child, rel_mu, rel_sigma,
        (const float4*)eps, beta, rels,
        out0, (float4*)out1, out2, (float4*)out3,
        N, nmu);
}